// Round 11
// baseline (67.469 us; speedup 1.0000x reference)
//
#include <hip/hip_runtime.h>

#define NB 16
#define NS 1024
#define NHID 64
#define NHEADS 4
#define NDH 16
#define LN_EPS 1e-5f
#define QSCALE 0.18033688011112f   // 0.125 * log2(e): folded into qh -> exp2f

using v2h  = __attribute__((ext_vector_type(2))) _Float16;
using v4h  = __attribute__((ext_vector_type(4))) _Float16;
using v4f  = __attribute__((ext_vector_type(4))) float;

__device__ __forceinline__ v4h cvt4h(float4 a) {
    v4h r; r[0] = (_Float16)a.x; r[1] = (_Float16)a.y;
    r[2] = (_Float16)a.z; r[3] = (_Float16)a.w; return r;
}

// ---------------------------------------------------------------------------
// Kernel 1 (qkv_mfma): as round 10, but qh is pre-scaled by 0.125*log2(e)
// so attention uses exp2f(st) with zero extra multiplies.
// ---------------------------------------------------------------------------
__global__ __launch_bounds__(256) void qkv_mfma_kernel(
    const float* __restrict__ x,
    const float* __restrict__ Wq, const float* __restrict__ bq,
    const float* __restrict__ Wk, const float* __restrict__ bk,
    const float* __restrict__ Wv, const float* __restrict__ bv,
    _Float16* __restrict__ qh, _Float16* __restrict__ kh,
    _Float16* __restrict__ vt)
{
    const int t = threadIdx.x;
    const int w = t >> 6, l = t & 63;
    const int n16 = l & 15, g = l >> 4;
    const int rt = (int)blockIdx.x * 4 + w;
    const int srow0 = rt * 16;
    const int b = srow0 >> 10, s0 = srow0 & 1023;
    const size_t sg = (size_t)srow0 + n16;

    v4h xa[4];
    #pragma unroll
    for (int kb = 0; kb < 4; ++kb)
        xa[kb] = cvt4h(*(const float4*)&x[sg * 64 + kb * 16 + 4 * g]);

    #pragma unroll
    for (int m = 0; m < 3; ++m) {
        const float* W  = (m == 0) ? Wq : (m == 1) ? Wk : Wv;
        const float* bb = (m == 0) ? bq : (m == 1) ? bk : bv;
        #pragma unroll
        for (int mb = 0; mb < 4; ++mb) {
            const float4 bv4 = *(const float4*)&bb[mb * 16 + 4 * g];
            v4f acc = {bv4.x, bv4.y, bv4.z, bv4.w};
            #pragma unroll
            for (int kb = 0; kb < 4; ++kb) {
                v4h wf = cvt4h(*(const float4*)&W[(size_t)(mb * 16 + n16) * 64 + kb * 16 + 4 * g]);
                acc = __builtin_amdgcn_mfma_f32_16x16x16f16(wf, xa[kb], acc, 0, 0, 0);
            }
            const size_t hb = (size_t)(b * NHEADS + mb);
            if (m == 0) {
                v4h r = {(_Float16)(acc[0] * QSCALE), (_Float16)(acc[1] * QSCALE),
                         (_Float16)(acc[2] * QSCALE), (_Float16)(acc[3] * QSCALE)};
                *(v4h*)&qh[(hb * NS + s0 + n16) * NDH + 4 * g] = r;
            } else if (m == 1) {
                v4h r = {(_Float16)acc[0], (_Float16)acc[1], (_Float16)acc[2], (_Float16)acc[3]};
                *(v4h*)&kh[(hb * NS + s0 + n16) * NDH + 4 * g] = r;
            } else {
                #pragma unroll
                for (int i = 0; i < 4; ++i)
                    vt[(hb * NDH + 4 * g + i) * NS + s0 + n16] = (_Float16)acc[i];
            }
        }
    }
}

// ---------------------------------------------------------------------------
// Kernel 2 (attn9): attn8 structure with VALU/barrier trims:
//  - exp2f on pre-scaled scores (no per-element scale mul)
//  - wave-uniform fast path skips masks on fully-valid subtiles
//  - P staged to LDS as f16 (same v4h as the PV fragment), parity
//    double-buffered -> ONE barrier per tile (was two)
//  - flush by all 1024 threads at float2 grain, 0.25 folded into flush
// ---------------------------------------------------------------------------
__global__ __launch_bounds__(1024, 8) void attn9_kernel(
    const _Float16* __restrict__ qh, const _Float16* __restrict__ kh,
    const _Float16* __restrict__ vt, const int* __restrict__ lengths,
    float* __restrict__ amean,   // [B,S,S]
    float* __restrict__ out)     // [B,S,64]
{
    __shared__ __align__(16) _Float16 Plds[2][2][NHEADS][16][72]; // [par][side][h][q][kcol]
    __shared__ float zlds[4][NHEADS][16][2];

    const int t = threadIdx.x;
    const int wv = t >> 6;
    const int h  = wv & 3;
    const int kq = wv >> 2;
    const int l  = t & 63;
    const int g = l >> 4, n16 = l & 15;
    const int pr = blockIdx.x, b = blockIdx.y;
    const int len = lengths[b];
    const int q0A = pr << 4, q0B = (63 - pr) << 4;
    const int qA_ = q0A + n16, qB_ = q0B + n16;
    const bool qvA = qA_ < len, qvB = qB_ < len;
    const bool lenFA = len >= q0A + 16, lenFB = len >= q0B + 16;

    const size_t hbase = ((size_t)(b * NHEADS + h)) * NS;
    const v4h QA = *(const v4h*)&qh[(hbase + qA_) * NDH + 4 * g];
    const v4h QB = *(const v4h*)&qh[(hbase + qB_) * NDH + 4 * g];

    const int nkA = (len <= q0A) ? 0 : min(q0A + 16, len);
    const int nkB = (len <= q0B) ? 0 : min(q0B + 16, len);
    const int ntA = (nkA + 63) >> 6, ntB = (nkB + 63) >> 6;
    const int ntM = max(ntA, ntB);
    const v4f z4v = {0.f, 0.f, 0.f, 0.f};

    // ---------------- pass 1: Z ----------------
    float ZA = 0.f, ZB = 0.f;
    for (int tile = 0; tile < ntM; ++tile) {
        const int ks = (tile << 6) + (kq << 4);
        const bool aA = ks < nkA, aB = ks < nkB;
        if (!aA && !aB) continue;
        const v4h K = *(const v4h*)&kh[(hbase + ks + n16) * NDH + 4 * g];
        if (aA) {
            v4f st = __builtin_amdgcn_mfma_f32_16x16x16f16(K, QA, z4v, 0, 0, 0);
            if (lenFA && (ks + 15 <= q0A)) {
                ZA += exp2f(st[0]) + exp2f(st[1]) + exp2f(st[2]) + exp2f(st[3]);
            } else {
                #pragma unroll
                for (int i = 0; i < 4; ++i) {
                    int kg = ks + 4 * g + i;
                    ZA += (qvA && kg <= qA_) ? exp2f(st[i]) : 0.f;
                }
            }
        }
        if (aB) {
            v4f st = __builtin_amdgcn_mfma_f32_16x16x16f16(K, QB, z4v, 0, 0, 0);
            if (lenFB && (ks + 15 <= q0B)) {
                ZB += exp2f(st[0]) + exp2f(st[1]) + exp2f(st[2]) + exp2f(st[3]);
            } else {
                #pragma unroll
                for (int i = 0; i < 4; ++i) {
                    int kg = ks + 4 * g + i;
                    ZB += (qvB && kg <= qB_) ? exp2f(st[i]) : 0.f;
                }
            }
        }
    }
    ZA += __shfl_xor(ZA, 16, 64); ZA += __shfl_xor(ZA, 32, 64);
    ZB += __shfl_xor(ZB, 16, 64); ZB += __shfl_xor(ZB, 32, 64);
    if (l < 16) {
        zlds[kq][h][n16][0] = ZA;
        zlds[kq][h][n16][1] = ZB;
    }
    __syncthreads();
    const float ztA = zlds[0][h][n16][0] + zlds[1][h][n16][0]
                    + zlds[2][h][n16][0] + zlds[3][h][n16][0];
    const float ztB = zlds[0][h][n16][1] + zlds[1][h][n16][1]
                    + zlds[2][h][n16][1] + zlds[3][h][n16][1];
    const float izA = (ztA > 0.f) ? 1.f / ztA : 0.f;
    const float izB = (ztB > 0.f) ? 1.f / ztB : 0.f;

    // ---------------- pass 2: P, amean, PV (1 barrier/tile) ----------------
    v4f oA = z4v, oB = z4v;
    const int pc = (kq << 4) + 4 * g;
    for (int tile = 0; tile < ntM; ++tile) {
        const int k0 = tile << 6;
        const int ks = k0 + (kq << 4);
        const int par = tile & 1;
        const bool aA = ks < nkA, aB = ks < nkB;
        v4h phA = {(_Float16)0.f, (_Float16)0.f, (_Float16)0.f, (_Float16)0.f};
        v4h phB = phA;
        if (aA || aB) {
            const v4h K = *(const v4h*)&kh[(hbase + ks + n16) * NDH + 4 * g];
            const v4h V = *(const v4h*)&vt[(((size_t)(b * NHEADS + h)) * NDH + n16) * NS + ks + 4 * g];
            if (aA) {
                v4f st = __builtin_amdgcn_mfma_f32_16x16x16f16(K, QA, z4v, 0, 0, 0);
                float p0, p1, p2, p3;
                if (lenFA && (ks + 15 <= q0A)) {
                    p0 = exp2f(st[0]) * izA; p1 = exp2f(st[1]) * izA;
                    p2 = exp2f(st[2]) * izA; p3 = exp2f(st[3]) * izA;
                } else {
                    const int kg = ks + 4 * g;
                    p0 = (qvA && kg + 0 <= qA_) ? exp2f(st[0]) * izA : 0.f;
                    p1 = (qvA && kg + 1 <= qA_) ? exp2f(st[1]) * izA : 0.f;
                    p2 = (qvA && kg + 2 <= qA_) ? exp2f(st[2]) * izA : 0.f;
                    p3 = (qvA && kg + 3 <= qA_) ? exp2f(st[3]) * izA : 0.f;
                }
                phA[0] = (_Float16)p0; phA[1] = (_Float16)p1;
                phA[2] = (_Float16)p2; phA[3] = (_Float16)p3;
                oA = __builtin_amdgcn_mfma_f32_16x16x16f16(phA, V, oA, 0, 0, 0);
            }
            if (aB) {
                v4f st = __builtin_amdgcn_mfma_f32_16x16x16f16(K, QB, z4v, 0, 0, 0);
                float p0, p1, p2, p3;
                if (lenFB && (ks + 15 <= q0B)) {
                    p0 = exp2f(st[0]) * izB; p1 = exp2f(st[1]) * izB;
                    p2 = exp2f(st[2]) * izB; p3 = exp2f(st[3]) * izB;
                } else {
                    const int kg = ks + 4 * g;
                    p0 = (qvB && kg + 0 <= qB_) ? exp2f(st[0]) * izB : 0.f;
                    p1 = (qvB && kg + 1 <= qB_) ? exp2f(st[1]) * izB : 0.f;
                    p2 = (qvB && kg + 2 <= qB_) ? exp2f(st[2]) * izB : 0.f;
                    p3 = (qvB && kg + 3 <= qB_) ? exp2f(st[3]) * izB : 0.f;
                }
                phB[0] = (_Float16)p0; phB[1] = (_Float16)p1;
                phB[2] = (_Float16)p2; phB[3] = (_Float16)p3;
                oB = __builtin_amdgcn_mfma_f32_16x16x16f16(phB, V, oB, 0, 0, 0);
            }
        }
        // unconditional write (zeros for inactive subtiles keep flush exact)
        *(v4h*)&Plds[par][0][h][n16][pc] = phA;
        *(v4h*)&Plds[par][1][h][n16][pc] = phB;
        __syncthreads();
        // flush this tile (parity buffer protects against next-iter writes)
        {
            const int sid = t >> 9, r = (t >> 5) & 15, c2 = (t & 31) * 2;
            const bool go = (sid == 0) ? (tile < ntA) : (tile < ntB);
            if (go) {
                float s0 = 0.f, s1 = 0.f;
                #pragma unroll
                for (int hh = 0; hh < 4; ++hh) {
                    v2h pv = *(const v2h*)&Plds[par][sid][hh][r][c2];
                    s0 += (float)pv[0]; s1 += (float)pv[1];
                }
                const int q0 = sid ? q0B : q0A;
                float2 wv2 = make_float2(0.25f * s0, 0.25f * s1);
                *(float2*)&amean[((size_t)(b * NS + q0 + r)) * NS + k0 + c2] = wv2;
            }
        }
    }
    __syncthreads();   // all flush reads done before obuf aliases Plds

    // ---------------- O cross-kq reduce (obuf aliases Plds) ----------------
    float* obuf = (float*)Plds;          // 16*64*8 f32 = 32 KB < 36.8 KB
    {
        float* p = &obuf[(wv * 64 + l) * 8];
        p[0] = oA[0]; p[1] = oA[1]; p[2] = oA[2]; p[3] = oA[3];
        p[4] = oB[0]; p[5] = oB[1]; p[6] = oB[2]; p[7] = oB[3];
    }
    __syncthreads();
    if (kq == 0) {
        #pragma unroll
        for (int kq2 = 1; kq2 < 4; ++kq2) {
            const float* p = &obuf[(((h + 4 * kq2) * 64) + l) * 8];
            oA[0] += p[0]; oA[1] += p[1]; oA[2] += p[2]; oA[3] += p[3];
            oB[0] += p[4]; oB[1] += p[5]; oB[2] += p[6]; oB[3] += p[7];
        }
        #pragma unroll
        for (int i = 0; i < 4; ++i) {
            out[((size_t)(b * NS) + q0A + 4 * g + i) * NHID + h * 16 + n16] = oA[i];
            out[((size_t)(b * NS) + q0B + 4 * g + i) * NHID + h * 16 + n16] = oB[i];
        }
    }

    // ---------------- amean zero-fill beyond processed tiles ----------------
    const float4 zf = make_float4(0.f, 0.f, 0.f, 0.f);
    {
        const int kzA = ntA << 6;
        const int nzA = (NS - kzA) >> 2;
        for (int r = 0; r < 16; ++r)
            for (int c4 = t; c4 < nzA; c4 += 1024)
                *(float4*)&amean[((size_t)(b * NS + q0A + r)) * NS + kzA + c4 * 4] = zf;
        const int kzB = ntB << 6;
        const int nzB = (NS - kzB) >> 2;
        for (int r = 0; r < 16; ++r)
            for (int c4 = t; c4 < nzB; c4 += 1024)
                *(float4*)&amean[((size_t)(b * NS + q0B + r)) * NS + kzB + c4 * 4] = zf;
    }
}

// ---------------------------------------------------------------------------
// Kernel 3 (ffn_mfma): unchanged from round 10.
// ---------------------------------------------------------------------------
__global__ __launch_bounds__(256) void ffn_mfma_kernel(
    const float* __restrict__ x, const float* __restrict__ aout,
    const float* __restrict__ W1, const float* __restrict__ b1,
    const float* __restrict__ W2, const float* __restrict__ b2,
    const float* __restrict__ g1, const float* __restrict__ be1,
    const float* __restrict__ g2, const float* __restrict__ be2,
    float* __restrict__ y)
{
    const int t = threadIdx.x;
    const int w = t >> 6, l = t & 63;
    const int n16 = l & 15, g = l >> 4;
    const int rt = (int)blockIdx.x * 4 + w;
    const size_t row = (size_t)rt * 16 + n16;

    float4 o1f[4];
    #pragma unroll
    for (int kb = 0; kb < 4; ++kb) {
        float4 xv = *(const float4*)&x[row * 64 + kb * 16 + 4 * g];
        float4 av = *(const float4*)&aout[row * 64 + kb * 16 + 4 * g];
        o1f[kb] = make_float4(xv.x + av.x, xv.y + av.y, xv.z + av.z, xv.w + av.w);
    }
    float s = 0.f;
    #pragma unroll
    for (int kb = 0; kb < 4; ++kb) s += o1f[kb].x + o1f[kb].y + o1f[kb].z + o1f[kb].w;
    s += __shfl_xor(s, 16, 64); s += __shfl_xor(s, 32, 64);
    const float mu = s * (1.f / 64.f);
    float vs = 0.f;
    #pragma unroll
    for (int kb = 0; kb < 4; ++kb) {
        float a = o1f[kb].x - mu, bq_ = o1f[kb].y - mu, c = o1f[kb].z - mu, d = o1f[kb].w - mu;
        vs += a * a + bq_ * bq_ + c * c + d * d;
    }
    vs += __shfl_xor(vs, 16, 64); vs += __shfl_xor(vs, 32, 64);
    const float rs = rsqrtf(vs * (1.f / 64.f) + LN_EPS);

    float4 n1v[4]; v4h n1h[4];
    #pragma unroll
    for (int kb = 0; kb < 4; ++kb) {
        float4 gv  = *(const float4*)&g1[kb * 16 + 4 * g];
        float4 bev = *(const float4*)&be1[kb * 16 + 4 * g];
        n1v[kb].x = (o1f[kb].x - mu) * rs * gv.x + bev.x;
        n1v[kb].y = (o1f[kb].y - mu) * rs * gv.y + bev.y;
        n1v[kb].z = (o1f[kb].z - mu) * rs * gv.z + bev.z;
        n1v[kb].w = (o1f[kb].w - mu) * rs * gv.w + bev.w;
        n1h[kb] = cvt4h(n1v[kb]);
    }

    v4h h1h[4];
    #pragma unroll
    for (int db = 0; db < 4; ++db) {
        const float4 b1v = *(const float4*)&b1[db * 16 + 4 * g];
        v4f acc = {b1v.x, b1v.y, b1v.z, b1v.w};
        #pragma unroll
        for (int kb = 0; kb < 4; ++kb) {
            v4h wf = cvt4h(*(const float4*)&W1[(size_t)(db * 16 + n16) * 64 + kb * 16 + 4 * g]);
            acc = __builtin_amdgcn_mfma_f32_16x16x16f16(wf, n1h[kb], acc, 0, 0, 0);
        }
        v4h hh;
        #pragma unroll
        for (int i = 0; i < 4; ++i) {
            float a = acc[i];
            hh[i] = (_Float16)(0.5f * a * (1.f + erff(a * 0.70710678118654752f)));
        }
        h1h[db] = hh;
    }

    float4 zf4[4];
    #pragma unroll
    for (int m2 = 0; m2 < 4; ++m2) {
        const float4 b2v = *(const float4*)&b2[m2 * 16 + 4 * g];
        v4f acc = {b2v.x, b2v.y, b2v.z, b2v.w};
        #pragma unroll
        for (int db = 0; db < 4; ++db) {
            v4h wf = cvt4h(*(const float4*)&W2[(size_t)(m2 * 16 + n16) * 64 + db * 16 + 4 * g]);
            acc = __builtin_amdgcn_mfma_f32_16x16x16f16(wf, h1h[db], acc, 0, 0, 0);
        }
        zf4[m2] = make_float4(n1v[m2].x + acc[0], n1v[m2].y + acc[1],
                              n1v[m2].z + acc[2], n1v[m2].w + acc[3]);
    }

    float s2 = 0.f;
    #pragma unroll
    for (int m2 = 0; m2 < 4; ++m2) s2 += zf4[m2].x + zf4[m2].y + zf4[m2].z + zf4[m2].w;
    s2 += __shfl_xor(s2, 16, 64); s2 += __shfl_xor(s2, 32, 64);
    const float mu2 = s2 * (1.f / 64.f);
    float vs2 = 0.f;
    #pragma unroll
    for (int m2 = 0; m2 < 4; ++m2) {
        float a = zf4[m2].x - mu2, bq_ = zf4[m2].y - mu2, c = zf4[m2].z - mu2, d = zf4[m2].w - mu2;
        vs2 += a * a + bq_ * bq_ + c * c + d * d;
    }
    vs2 += __shfl_xor(vs2, 16, 64); vs2 += __shfl_xor(vs2, 32, 64);
    const float rs2 = rsqrtf(vs2 * (1.f / 64.f) + LN_EPS);
    #pragma unroll
    for (int m2 = 0; m2 < 4; ++m2) {
        float4 gv  = *(const float4*)&g2[m2 * 16 + 4 * g];
        float4 bev = *(const float4*)&be2[m2 * 16 + 4 * g];
        float4 yv;
        yv.x = (zf4[m2].x - mu2) * rs2 * gv.x + bev.x;
        yv.y = (zf4[m2].y - mu2) * rs2 * gv.y + bev.y;
        yv.z = (zf4[m2].z - mu2) * rs2 * gv.z + bev.z;
        yv.w = (zf4[m2].w - mu2) * rs2 * gv.w + bev.w;
        *(float4*)&y[row * 64 + m2 * 16 + 4 * g] = yv;
    }
}

// ---------------------------------------------------------------------------
extern "C" void kernel_launch(void* const* d_in, const int* in_sizes, int n_in,
                              void* d_out, int out_size, void* d_ws, size_t ws_size,
                              hipStream_t stream) {
    const float* x   = (const float*)d_in[0];
    const int* lengths = (const int*)d_in[1];
    const float* Wq  = (const float*)d_in[3];
    const float* bq  = (const float*)d_in[4];
    const float* Wk  = (const float*)d_in[5];
    const float* bk  = (const float*)d_in[6];
    const float* Wv  = (const float*)d_in[7];
    const float* bv  = (const float*)d_in[8];
    const float* W1  = (const float*)d_in[9];
    const float* b1  = (const float*)d_in[10];
    const float* W2  = (const float*)d_in[11];
    const float* b2  = (const float*)d_in[12];
    const float* g1  = (const float*)d_in[13];
    const float* be1 = (const float*)d_in[14];
    const float* g2  = (const float*)d_in[15];
    const float* be2 = (const float*)d_in[16];

    float* y     = (float*)d_out;                       // [B,S,64]
    float* amean = y + (size_t)NB * NS * NHID;          // [B,S,S]

    const size_t nqkv = (size_t)NB * NHEADS * NS * NDH; // 1,048,576 elems
    _Float16* qhw = (_Float16*)d_ws;                    // f16 [B,NH,S,16] (pre-scaled)
    _Float16* khw = qhw + nqkv;
    _Float16* vtw = khw + nqkv;                         // f16 [B,NH,16,S]
    float* aoutw  = (float*)(vtw + nqkv);               // fp32 [B,S,64]

    hipLaunchKernelGGL(qkv_mfma_kernel, dim3(NB * NS / 64), dim3(256), 0, stream,
                       x, Wq, bq, Wk, bk, Wv, bv, qhw, khw, vtw);
    hipLaunchKernelGGL(attn9_kernel, dim3(32, NB), dim3(1024), 0, stream,
                       qhw, khw, vtw, lengths, amean, aoutw);
    hipLaunchKernelGGL(ffn_mfma_kernel, dim3(NB * NS / 64), dim3(256), 0, stream,
                       x, aoutw, W1, b1, W2, b2, g1, be1, g2, be2, y);
}